// Round 5
// baseline (3175.382 us; speedup 1.0000x reference)
//
#include <hip/hip_runtime.h>

#define D_IN 512
#define D_H 1024
#define D_OUT 32000
#define NB 64
#define NS 512

typedef __attribute__((ext_vector_type(8))) short short8;
typedef __attribute__((ext_vector_type(8))) __bf16 bf16x8;
typedef __attribute__((ext_vector_type(4))) float f32x4;
typedef __attribute__((ext_vector_type(4))) unsigned int u32x4;

__device__ __forceinline__ unsigned short f2bf(float f) {
  unsigned int u = __float_as_uint(f);
  u += 0x7fffu + ((u >> 16) & 1u);
  return (unsigned short)(u >> 16);
}
__device__ __forceinline__ float bf2f(unsigned short s) {
  return __uint_as_float(((unsigned int)s) << 16);
}

__device__ __forceinline__ f32x4 mfma_bf16(short8 a, short8 b, f32x4 c) {
  return __builtin_amdgcn_mfma_f32_16x16x32_bf16(
      __builtin_bit_cast(bf16x8, a), __builtin_bit_cast(bf16x8, b), c, 0, 0, 0);
}

// ---- agent-coherent ops (bypass L1+L2 to the Infinity Cache; same strength
// as __hip_atomic_* AGENT, which round 1 verified end-to-end) ----------------
__device__ __forceinline__ u32x4 ld16_cc(const void* p) {
  u32x4 v;
  asm volatile("global_load_dwordx4 %0, %1, off sc0 sc1"
               : "=v"(v) : "v"(p) : "memory");
  return v;
}
__device__ __forceinline__ void st8_cc(void* p, unsigned long long v) {
  asm volatile("global_store_dwordx2 %0, %1, off sc0 sc1"
               :: "v"(p), "v"(v) : "memory");
}

// ---------------------------------------------------------------------------
// h exchange: fp32 words, PER-WORD step tag in bit 30 (free since |h|<=1 ->
// fp32 exponent < 128 -> bit30 == 0).  Word = f32bits(h) | tag<<30 where
// tag(tau) = (tau>>1)&1.  Consumer at step t expects tag ((t-1)>>1)&1; the
// only other value the buffer can hold is tau = t-3 (opposite tag), because
// our own step t-2 validated every word of this buffer as tau = t-3, and no
// peer can write tau = t+1 before consuming our (unpublished) tau = t chunk.
// Every dword is individually atomic -> NO multi-word atomicity assumption.
//
// hexw layout (words): [g(4)][buf(2)][chunk(32)][b(16)][kk(32)]
//   chunk block = 2KB; word (b,kk) at byte b*128 + kk*4.
// rnn_init: buf0 = h0 with tag 0, buf1 = sentinel tag 1 (graph-replay safe).
// ---------------------------------------------------------------------------
__global__ __launch_bounds__(256) void rnn_init(const float* __restrict__ h0,
                                                unsigned int* __restrict__ hexw) {
  int idx = blockIdx.x * 256 + threadIdx.x;  // 0..131071
  int kk = idx & 31;
  int b = (idx >> 5) & 15;
  int c = (idx >> 9) & 31;
  int buf = (idx >> 14) & 1;
  int g = idx >> 15;
  unsigned w;
  if (buf == 0) {
    float v = h0[(size_t)(g * 16 + b) * 1024 + c * 32 + kk];
    w = __float_as_uint(v) & 0xBFFFFFFFu;  // tag 0 (= tag of "step 0")
  } else {
    w = 0x40000000u;                        // sentinel: tag 1, payload 0
  }
  hexw[idx] = w;  // plain store: kernel-boundary flush publishes it
}

// ---------------------------------------------------------------------------
// pack W_ih [512][1024] fp32 -> B-fragment layout, hi/lo bf16 planes
// ---------------------------------------------------------------------------
__global__ __launch_bounds__(256) void rnn_pack_wih(const float* __restrict__ W_ih,
                                                    unsigned short* __restrict__ bhi,
                                                    unsigned short* __restrict__ blo) {
  int idx = blockIdx.x * 256 + threadIdx.x;  // 0..524287
  int j = idx & 7;
  int l = (idx >> 3) & 63;
  int kc = (idx >> 9) & 15;
  int nc = idx >> 13;
  int k = kc * 32 + ((l >> 4) << 3) + j;
  int n = nc * 16 + (l & 15);
  float v = W_ih[(size_t)k * D_H + n];
  unsigned short h = f2bf(v);
  bhi[idx] = h;
  blo[idx] = f2bf(v - bf2f(h));
}

// ---------------------------------------------------------------------------
// stage 1: xw[t*64+b][n] = embed[tokens[b][t]] @ W_ih + bias_hh   (bf16x3 MFMA)
// ---------------------------------------------------------------------------
__global__ __launch_bounds__(256) void rnn_stage1(const int* __restrict__ tokens,
                                                  const float* __restrict__ embed,
                                                  const unsigned short* __restrict__ bhi,
                                                  const unsigned short* __restrict__ blo,
                                                  const float* __restrict__ bias,
                                                  float* __restrict__ xw) {
  int bx = blockIdx.x;
  int mt = bx >> 4, nt = bx & 15;
  int tid = threadIdx.x;
  int w = tid >> 6, l = tid & 63;
  int q = l >> 4;

  int m = mt * 64 + w * 16 + (l & 15);  // A-operand row
  int b = m & 63, t = m >> 6;
  int tok = tokens[b * NS + t];
  const float* arow = embed + (size_t)tok * D_IN;

  f32x4 acc[4];
#pragma unroll
  for (int i = 0; i < 4; ++i) acc[i] = (f32x4){0.f, 0.f, 0.f, 0.f};

  for (int c = 0; c < 16; ++c) {
    const float* ap = arow + c * 32 + q * 8;
    float4 f0 = *(const float4*)ap;
    float4 f1 = *(const float4*)(ap + 4);
    float fa[8] = {f0.x, f0.y, f0.z, f0.w, f1.x, f1.y, f1.z, f1.w};
    short8 ahi, alo;
#pragma unroll
    for (int j = 0; j < 8; ++j) {
      unsigned short hh = f2bf(fa[j]);
      ahi[j] = (short)hh;
      alo[j] = (short)f2bf(fa[j] - bf2f(hh));
    }
#pragma unroll
    for (int ni = 0; ni < 4; ++ni) {
      int ncg = nt * 4 + ni;
      size_t boff = ((size_t)(ncg * 16 + c) * 64 + l) * 8;
      short8 bh = *(const short8*)(bhi + boff);
      short8 bl_ = *(const short8*)(blo + boff);
      acc[ni] = mfma_bf16(ahi, bh, acc[ni]);
      acc[ni] = mfma_bf16(alo, bh, acc[ni]);
      acc[ni] = mfma_bf16(ahi, bl_, acc[ni]);
    }
  }

#pragma unroll
  for (int ni = 0; ni < 4; ++ni) {
    int col = nt * 64 + ni * 16 + (l & 15);
    float bv = bias[col];
#pragma unroll
    for (int r = 0; r < 4; ++r) {
      int row = mt * 64 + w * 16 + q * 4 + r;  // D-layout row
      xw[(size_t)row * D_H + col] = acc[ni][r] + bv;
    }
  }
}

// split 8 fp32 h-words (tag bit cleared) to bf16 hi/lo and fold 6 MFMAs
#define CONSUME_W(Wa, cc)                                              \
  {                                                                    \
    short8 ah_, al_;                                                   \
    _Pragma("unroll")                                                  \
    for (int m_ = 0; m_ < 8; ++m_) {                                   \
      float v_ = __uint_as_float(Wa[m_] & 0xBFFFFFFFu);                \
      unsigned short hh_ = f2bf(v_);                                   \
      ah_[m_] = (short)hh_;                                            \
      al_[m_] = (short)f2bf(v_ - bf2f(hh_));                           \
    }                                                                  \
    short8 bh0_ = *(const short8*)(Whi + (cc) * 512 + l * 8);          \
    short8 bl0_ = *(const short8*)(Wlo + (cc) * 512 + l * 8);          \
    short8 bh1_ = *(const short8*)(Whi + 16384 + (cc) * 512 + l * 8);  \
    short8 bl1_ = *(const short8*)(Wlo + 16384 + (cc) * 512 + l * 8);  \
    a00 = mfma_bf16(ah_, bh0_, a00);                                   \
    a01 = mfma_bf16(al_, bh0_, a01);                                   \
    a02 = mfma_bf16(ah_, bl0_, a02);                                   \
    a10 = mfma_bf16(ah_, bh1_, a10);                                   \
    a11 = mfma_bf16(al_, bh1_, a11);                                   \
    a12 = mfma_bf16(ah_, bl1_, a12);                                   \
  }

// ---------------------------------------------------------------------------
// stage 2: persistent recurrence, per-word-tagged fp32 exchange.
// 128 WGs = 4 batch-groups x 32 j-tiles; wave w consumes chunks w*8..w*8+7.
// Producer epilogue is fire-and-forget (tag rides in every dword).  Consumer
// reloads pending chunks (2 x dwordx4 per lane) and accepts a chunk when all
// 512 of its words carry the expected tag (__all over 64 lanes x 8 words).
// Own chunk is consumed from LDS floats (ownF), skipping global entirely.
// ---------------------------------------------------------------------------
__global__ __launch_bounds__(256, 1) void rnn_recur(const float* __restrict__ xw,
                                                    const float* __restrict__ W_hh,
                                                    unsigned int* __restrict__ hexw,
                                                    float* __restrict__ h_last) {
  __shared__ short Whi[32768];        // 64 KB
  __shared__ short Wlo[32768];        // 64 KB
  __shared__ float red[4][16][33];    // 8448 B
  __shared__ float ownF[16 * 33];     // 2112 B (own-chunk h, padded)

  const int tid = threadIdx.x;
  const int bx = blockIdx.x;
  const int g = bx >> 5;     // batch group 0..3
  const int jt = bx & 31;    // j tile == produced chunk id
  const int jcol0 = jt * 32;
  const int w = tid >> 6;
  const int l = tid & 63;
  const int q = l >> 4;
  const int b_lane = l & 15;

  // one-time: load + split W_hh slice into LDS in B-fragment order.
  for (int v = tid; v < 32768; v += 256) {
    int j = v & 7;
    int ll = (v >> 3) & 63;
    int c = (v >> 9) & 31;
    int s2 = v >> 14;
    int k = c * 32 + ((ll >> 4) << 3) + j;
    int n = s2 * 16 + (ll & 15);
    float wv = W_hh[(size_t)k * D_H + jcol0 + n];
    unsigned short hh = f2bf(wv);
    Whi[v] = (short)hh;
    Wlo[v] = (short)f2bf(wv - bf2f(hh));
  }

  const bool ownw = ((jt >> 3) == w);
  const unsigned ownbit = 1u << (jt & 7);
  const int loff = b_lane * 128 + q * 32;  // lane's byte offset in a chunk

  // epilogue constants: 2 adjacent j per thread (one dwordx2 store)
  const int be = tid >> 4;            // batch 0..15
  const int je2 = (tid & 15) * 2;     // j 0,2,..,30
  const int brow = g * 16 + be;

  char* hexb = (char*)hexw;

  // prologue prefetch for t=1
  float xv0, xv1;
  {
    const float* xwp = xw + (size_t)brow * D_H + jcol0 + je2;
    xv0 = xwp[0];
    xv1 = xwp[1];
  }
  __syncthreads();

  for (int t = 1; t <= NS; ++t) {
    const unsigned expw = (unsigned)(((t - 1) >> 1) & 1) << 30;
    const char* hb = hexb + (size_t)(g * 2 + ((t - 1) & 1)) * 65536;

    f32x4 a00 = {0.f, 0.f, 0.f, 0.f}, a01 = a00, a02 = a00;
    f32x4 a10 = a00, a11 = a00, a12 = a00;

    const bool useown = ownw && (t > 1);
    unsigned need = useown ? (255u & ~ownbit) : 255u;
    bool first = true;
    u32x4 GA[8], GB[8];

    while (need) {
      const unsigned m0 = need;
      // ---- issue reloads for all pending chunks (pipelined) ----
#pragma unroll
      for (int i = 0; i < 8; ++i) {
        if (m0 & (1u << i)) {
          const char* cb = hb + (size_t)(w * 8 + i) * 2048 + loff;
          GA[i] = ld16_cc(cb);
          GB[i] = ld16_cc(cb + 16);
        }
      }
      // own chunk from LDS overlaps the in-flight loads
      if (first && useown) {
        unsigned Wo[8];
#pragma unroll
        for (int m_ = 0; m_ < 8; ++m_)
          Wo[m_] = __float_as_uint(ownF[b_lane * 33 + q * 8 + m_]);
        CONSUME_W(Wo, jt);
      }
      asm volatile("s_waitcnt vmcnt(0)" ::: "memory");
      __builtin_amdgcn_sched_barrier(0);  // rule #18: pin uses below waitcnt

      // ---- validate per word (bit30 == expected tag), accept, consume ----
#pragma unroll
      for (int i = 0; i < 8; ++i) {
        if (m0 & (1u << i)) {
          unsigned bad = (GA[i].x ^ expw) | (GA[i].y ^ expw) |
                         (GA[i].z ^ expw) | (GA[i].w ^ expw) |
                         (GB[i].x ^ expw) | (GB[i].y ^ expw) |
                         (GB[i].z ^ expw) | (GB[i].w ^ expw);
          if (__all((int)((bad & 0x40000000u) == 0u))) {
            need &= ~(1u << i);
            unsigned W_[8] = {GA[i].x, GA[i].y, GA[i].z, GA[i].w,
                              GB[i].x, GB[i].y, GB[i].z, GB[i].w};
            CONSUME_W(W_, w * 8 + i);
          }
        }
      }
      first = false;
    }

    f32x4 s0 = a00 + a01 + a02;
    f32x4 s1 = a10 + a11 + a12;
#pragma unroll
    for (int r = 0; r < 4; ++r) {
      red[w][q * 4 + r][b_lane] = s0[r];
      red[w][q * 4 + r][16 + b_lane] = s1[r];
    }
    __syncthreads();

    // ---- epilogue: every thread handles (be, je2) and (be, je2+1) ----
    float z0 = red[0][be][je2] + red[1][be][je2] + red[2][be][je2] +
               red[3][be][je2] + xv0;
    float z1 = red[0][be][je2 + 1] + red[1][be][je2 + 1] + red[2][be][je2 + 1] +
               red[3][be][je2 + 1] + xv1;
    float hv0 = tanhf(z0);
    float hv1 = tanhf(z1);
    ownF[be * 33 + je2] = hv0;       // own-chunk fast path for t+1
    ownF[be * 33 + je2 + 1] = hv1;
    const unsigned tagw = (unsigned)((t >> 1) & 1) << 30;
    unsigned w0 = (__float_as_uint(hv0) & 0xBFFFFFFFu) | tagw;
    unsigned w1 = (__float_as_uint(hv1) & 0xBFFFFFFFu) | tagw;
    char* wb = hexb + (size_t)(g * 2 + (t & 1)) * 65536 + (size_t)jt * 2048 +
               be * 128 + je2 * 4;
    st8_cc(wb, (unsigned long long)w0 | ((unsigned long long)w1 << 32));
    // fire-and-forget: every dword self-tags; no drain, no flag

    if (t == NS) {
      h_last[(size_t)brow * 1024 + jcol0 + je2] = hv0;
      h_last[(size_t)brow * 1024 + jcol0 + je2 + 1] = hv1;
    } else {  // prefetch next xv (overlaps next poll phase)
      const float* xwp = xw + ((size_t)t * 64 + brow) * D_H + jcol0 + je2;
      xv0 = xwp[0];
      xv1 = xwp[1];
    }
    __syncthreads();
  }
}

// ---------------------------------------------------------------------------
// stage 3: y[b][j] = h_last[b][:] . W_out[:][j] + b_out[j]   (fp32 vector)
// ---------------------------------------------------------------------------
__global__ __launch_bounds__(256, 2) void rnn_out(const float* __restrict__ h_last,
                                                  const float* __restrict__ W_out,
                                                  const float* __restrict__ b_out,
                                                  float* __restrict__ out) {
  __shared__ float smem[16384];
  int tid = threadIdx.x;
  int jl = tid & 127;
  int kh = tid >> 7;
  int j = blockIdx.x * 128 + jl;

  float acc[64];
#pragma unroll
  for (int b = 0; b < 64; ++b) acc[b] = 0.f;

  for (int kc = 0; kc < 4; ++kc) {
    __syncthreads();
    for (int v = tid; v < 16384; v += 256) {
      int kh2 = v >> 13;
      int b = (v >> 7) & 63;
      int kk = v & 127;
      smem[v] = h_last[(size_t)b * 1024 + kh2 * 512 + kc * 128 + kk];
    }
    __syncthreads();
    int kbase = kh * 512 + kc * 128;
    for (int kkc = 0; kkc < 16; ++kkc) {
      float wreg[8];
#pragma unroll
      for (int i = 0; i < 8; ++i)
        wreg[i] = W_out[(size_t)(kbase + kkc * 8 + i) * D_OUT + j];
#pragma unroll
      for (int b = 0; b < 64; ++b) {
        const float* hp = &smem[kh * 8192 + b * 128 + kkc * 8];
#pragma unroll
        for (int i = 0; i < 8; ++i) acc[b] += hp[i] * wreg[i];
      }
    }
  }
  __syncthreads();
  if (kh == 1) {
#pragma unroll
    for (int b = 0; b < 64; ++b) smem[jl * 65 + b] = acc[b];
  }
  __syncthreads();
  if (kh == 0) {
    float bo = b_out[j];
#pragma unroll
    for (int b = 0; b < 64; ++b)
      out[(size_t)b * D_OUT + j] = acc[b] + smem[jl * 65 + b] + bo;
  }
}

// ---------------------------------------------------------------------------
extern "C" void kernel_launch(void* const* d_in, const int* in_sizes, int n_in,
                              void* d_out, int out_size, void* d_ws, size_t ws_size,
                              hipStream_t stream) {
  const int* tokens = (const int*)d_in[0];
  const float* h0 = (const float*)d_in[1];
  const float* embed = (const float*)d_in[2];
  const float* W_ih = (const float*)d_in[3];
  const float* W_hh = (const float*)d_in[4];
  const float* bias_hh = (const float*)d_in[5];
  const float* W_out = (const float*)d_in[6];
  const float* b_out = (const float*)d_in[7];
  float* out = (float*)d_out;

  char* ws = (char*)d_ws;
  // workspace layout (bytes)
  float* xw = (float*)(ws);                                   // 134217728
  unsigned short* wih_hi = (unsigned short*)(ws + 134217728); // 1048576
  unsigned short* wih_lo = (unsigned short*)(ws + 135266304); // 1048576
  unsigned int* hexw = (unsigned int*)(ws + 136314880);       // 524288 (tagged fp32 words)
  float* h_last = (float*)(ws + 136839168);                   // 262144
  // total: 137101312 bytes

  rnn_init<<<512, 256, 0, stream>>>(h0, hexw);
  rnn_pack_wih<<<2048, 256, 0, stream>>>(W_ih, wih_hi, wih_lo);
  rnn_stage1<<<8192, 256, 0, stream>>>(tokens, embed, wih_hi, wih_lo, bias_hh, xw);
  rnn_recur<<<128, 256, 0, stream>>>(xw, W_hh, hexw, h_last);
  rnn_out<<<250, 256, 0, stream>>>(h_last, W_out, b_out, out);
}